// Round 7
// baseline (678.301 us; speedup 1.0000x reference)
//
#include <hip/hip_runtime.h>
#include <hip/hip_bf16.h>

// out[b,s,o] = sum_k x[b,s,k] * W[o,k] + bias[o],  W[o,k] = sum_d codebook[idx[o,d]] * rot[k,d]
// bf16 path: dequant+convert, GEMM1 (W = Wr @ R^T, bf16 out), GEMM2 (out = X @ W^T + bias, f32).
// R7: 256x256 tile, BK=64, 8 waves (2Mx4N), 32x32x16 MFMA (2495 TF ceiling, -17% pipe cycles),
// 2-K-tile unrolled 8-phase loop (compile-time LDS addressing), 1 half-tile stage per phase,
// counted vmcnt(4) at ph4/ph8 only. T1 XCD swizzle, T2 row-XOR LDS swizzle, T5 setprio.
// Frag layouts (m74/m101/m89 verified): 32x32 C/D col=lane&31, row=(r&3)+8*(r>>2)+4*(lane>>5);
// A/B operand lane: row=lane&31, k=(lane>>5)*8+j (one ds_read_b128 per frag).

typedef __attribute__((ext_vector_type(8))) __bf16 bf16x8;
typedef __attribute__((ext_vector_type(16))) float f32x16;

#define GLOAD_LDS16(g, l)                                                        \
  __builtin_amdgcn_global_load_lds((__attribute__((address_space(1))) void*)(g), \
                                   (__attribute__((address_space(3))) void*)(l), \
                                   16, 0, 0)

// ---------------- conversion kernels ----------------

__global__ __launch_bounds__(256) void cvt_f32_bf16(const float* __restrict__ in,
                                                    __hip_bfloat16* __restrict__ out, int n4) {
  int i = blockIdx.x * 256 + threadIdx.x;
  if (i >= n4) return;
  float4 v = *(const float4*)(in + (size_t)i * 4);
  union { __hip_bfloat16 h[4]; ushort4 u; } o;
  o.h[0] = __float2bfloat16(v.x);
  o.h[1] = __float2bfloat16(v.y);
  o.h[2] = __float2bfloat16(v.z);
  o.h[3] = __float2bfloat16(v.w);
  *(ushort4*)((unsigned short*)out + (size_t)i * 4) = o.u;
}

__global__ __launch_bounds__(256) void dequant_bf16(const int* __restrict__ idx,
                                                    const float* __restrict__ cb,
                                                    __hip_bfloat16* __restrict__ out, int n4) {
  __shared__ __hip_bfloat16 scb[16];
  if (threadIdx.x < 16) scb[threadIdx.x] = __float2bfloat16(cb[threadIdx.x]);
  __syncthreads();
  int i = blockIdx.x * 256 + threadIdx.x;
  if (i >= n4) return;
  int4 v = *(const int4*)(idx + (size_t)i * 4);
  union { __hip_bfloat16 h[4]; ushort4 u; } o;
  o.h[0] = scb[v.x & 15];
  o.h[1] = scb[v.y & 15];
  o.h[2] = scb[v.z & 15];
  o.h[3] = scb[v.w & 15];
  *(ushort4*)((unsigned short*)out + (size_t)i * 4) = o.u;
}

// ---------------- 256^2 8-phase NT bf16 GEMM (32x32x16): C = A[M,K] @ B[N,K]^T ----------------
// LDS: 2 dbuf x (A[256][64] + B[256][64]) bf16 = 128 KiB. Half-tile = 128x64 = 2 gload/wave.
// Per wave: 128x64 out = 4 mi x 2 ni frags of 32x32 (acc 8 x f32x16 = 128 VGPR).
// Phase (tile t, mi-half MH, ks-half KH): reads A (mi in {2MH,2MH+1} x ks in {2KH,2KH+1}) [4],
//   B (ni x ks) [4, only when MH==0]; 1 half-tile stage; barrier; lgkm(0); 8 MFMA; barrier.
// Stage plan per iter (tiles E,E+1): ph1,2: A0,A1(E+1)->buf1 (last read prev ph8);
//   ph3,4: B0,B1(E+2)->buf0 (B buf0 last read ph2); ph5,6: A0,A1(E+2)->buf0 (A last read ph4);
//   ph7,8: B0,B1(E+3)->buf1 (last read ph6). vmcnt(4) at ph4 (need A(E+1) landed) and
//   ph8 (need B(E+2)+A(E+2) landed), leaving 2 half-tiles in flight.

template <bool OUT_BF16>
__global__ __launch_bounds__(512, 2) void gemm256(const __hip_bfloat16* __restrict__ A,
                                                  const __hip_bfloat16* __restrict__ B,
                                                  void* __restrict__ Cv,
                                                  const float* __restrict__ bias,
                                                  int M, int N, int K) {
  __shared__ __align__(16) char smem[131072];

  const int nbn = N >> 8;
  const int nwg = (M >> 8) * nbn;
  const int bid0 = blockIdx.x;
  const int cpx = nwg >> 3;  // nwg % 8 == 0 for our shapes -> bijective XCD swizzle
  const int bid = (bid0 & 7) * cpx + (bid0 >> 3);
  const int m0 = (bid / nbn) << 8;
  const int n0 = (bid % nbn) << 8;

  const int tid = (int)threadIdx.x;
  const int lane = tid & 63;
  const int w = tid >> 6;   // wave 0..7
  const int wr = w >> 2;    // 0..1 -> 128 rows
  const int wc = w & 3;     // 0..3 -> 64 cols
  const int ln31 = lane & 31;
  const int hi = lane >> 5;  // k-group

  // staging lane pattern: srow = row within 8-row stripe, scol = inverse-swizzled col
  const int srow = lane >> 3;                 // 0..7
  const int scol = ((lane & 7) ^ srow) << 3;  // element offset within 64-col row

  const __hip_bfloat16* Ab = A + (size_t)m0 * K;
  const __hip_bfloat16* Bb = B + (size_t)n0 * K;

  const int NT = K >> 6;

  f32x16 acc[4][2];
#pragma unroll
  for (int i = 0; i < 4; ++i)
#pragma unroll
    for (int j = 0; j < 2; ++j) acc[i][j] = (f32x16){};

  // stage half-tile s = 4*t + kind (kind: 0=A rows0-127, 1=A rows128-255, 2=B0, 3=B1)
  auto stage = [&](int s) {
    const int t = s >> 2, kind = s & 3;
    const __hip_bfloat16* g = (kind < 2) ? Ab : Bb;
    char* region = smem + ((kind < 2) ? 0 : 65536) + (t & 1) * 32768 + (kind & 1) * 16384;
    const int grow = (kind & 1) * 128 + w * 16 + srow;
    const int k0 = t << 6;
#pragma unroll
    for (int j = 0; j < 2; ++j)
      GLOAD_LDS16(g + (size_t)(grow + j * 8) * K + (k0 + scol), region + w * 2048 + j * 1024);
  };

  const int sw = (lane & 7) << 4;  // read-side swizzle XOR (row&7 == lane&7: bases are %8==0)

  // A frag (mi-th 32-row block, ks-th K=16 slice): row = wr*128 + mi*32 + ln31
  auto ldA32 = [&](int b, int mi, int ks) -> bf16x8 {
    const int row = wr * 128 + mi * 32 + ln31;
    const int byte = b * 32768 + row * 128 + ((ks * 32 + hi * 16) ^ sw);
    return *(const bf16x8*)(smem + byte);
  };
  // B frag (ni-th 32-col block): row = wc*64 + ni*32 + ln31
  auto ldB32 = [&](int b, int ni, int ks) -> bf16x8 {
    const int row = wc * 64 + ni * 32 + ln31;
    const int byte = 65536 + b * 32768 + row * 128 + ((ks * 32 + hi * 16) ^ sw);
    return *(const bf16x8*)(smem + byte);
  };

  bf16x8 af[2][2];      // A frags for current phase: [mi2][ks2]
  bf16x8 bk[2][2][2];   // persistent B frags: [KH][ni][ks2]

  // phase: BUF, MH (mi-half), KH (ks-half), stage_s (-1 = none), wait: 0 none, 4/0 = vmcnt
  auto phase = [&](int BUF, int MH, int KH, int stage_s, int wait) {
#pragma unroll
    for (int mi2 = 0; mi2 < 2; ++mi2)
#pragma unroll
      for (int ks2 = 0; ks2 < 2; ++ks2) af[mi2][ks2] = ldA32(BUF, MH * 2 + mi2, KH * 2 + ks2);
    if (MH == 0) {
#pragma unroll
      for (int ni = 0; ni < 2; ++ni)
#pragma unroll
        for (int ks2 = 0; ks2 < 2; ++ks2) bk[KH][ni][ks2] = ldB32(BUF, ni, KH * 2 + ks2);
    }
    if (stage_s >= 0) stage(stage_s);
    __builtin_amdgcn_s_barrier();
    asm volatile("s_waitcnt lgkmcnt(0)");
    __builtin_amdgcn_sched_barrier(0);
    __builtin_amdgcn_s_setprio(1);
#pragma unroll
    for (int ks2 = 0; ks2 < 2; ++ks2)
#pragma unroll
      for (int mi2 = 0; mi2 < 2; ++mi2)
#pragma unroll
        for (int ni = 0; ni < 2; ++ni)
          acc[MH * 2 + mi2][ni] = __builtin_amdgcn_mfma_f32_32x32x16_bf16(
              af[mi2][ks2], bk[KH][ni][ks2], acc[MH * 2 + mi2][ni], 0, 0, 0);
    __builtin_amdgcn_s_setprio(0);
    if (wait == 1) {
      asm volatile("s_waitcnt vmcnt(4)" ::: "memory");
    } else if (wait == 2) {
      asm volatile("s_waitcnt vmcnt(0)" ::: "memory");
    }
    __builtin_amdgcn_s_barrier();
  };

  // prologue: tile0 (A0,A1,B0,B1) + tile1 (B0,B1); wait tile0 landed, leave tile1.B in flight
  stage(0); stage(1); stage(2); stage(3);
  stage(6); stage(7);
  asm volatile("s_waitcnt vmcnt(4)" ::: "memory");
  __builtin_amdgcn_s_barrier();

  for (int E = 0; E < NT; E += 2) {
    const bool pf2 = (E + 2 < NT);
    // tile E (buf0)
    phase(0, 0, 0, 4 * (E + 1) + 0, 0);                    // ph1: stage A0(E+1)->buf1
    phase(0, 0, 1, 4 * (E + 1) + 1, 0);                    // ph2: stage A1(E+1)->buf1
    phase(0, 1, 0, pf2 ? 4 * (E + 2) + 2 : -1, 0);         // ph3: stage B0(E+2)->buf0
    phase(0, 1, 1, pf2 ? 4 * (E + 2) + 3 : -1, pf2 ? 1 : 2);  // ph4 + vmcnt(4|0)
    // tile E+1 (buf1)
    phase(1, 0, 0, pf2 ? 4 * (E + 2) + 0 : -1, 0);         // ph5: stage A0(E+2)->buf0
    phase(1, 0, 1, pf2 ? 4 * (E + 2) + 1 : -1, 0);         // ph6: stage A1(E+2)->buf0
    phase(1, 1, 0, pf2 ? 4 * (E + 3) + 2 : -1, 0);         // ph7: stage B0(E+3)->buf1
    phase(1, 1, 1, pf2 ? 4 * (E + 3) + 3 : -1, pf2 ? 1 : 0);  // ph8 + vmcnt(4) if pf2
  }

  // ---- epilogue: 32x32 C/D: col = lane&31, row = (r&3) + 8*(r>>2) + 4*hi  [m74/m101]
  if constexpr (OUT_BF16) {
    __hip_bfloat16* C = (__hip_bfloat16*)Cv;
#pragma unroll
    for (int mi = 0; mi < 4; ++mi)
#pragma unroll
      for (int ni = 0; ni < 2; ++ni) {
        const int colg = n0 + wc * 64 + ni * 32 + ln31;
#pragma unroll
        for (int r = 0; r < 16; ++r) {
          const int rowg = m0 + wr * 128 + mi * 32 + (r & 3) + 8 * (r >> 2) + 4 * hi;
          C[(size_t)rowg * N + colg] = __float2bfloat16(acc[mi][ni][r]);
        }
      }
  } else {
    float* C = (float*)Cv;
    float bv[2];
#pragma unroll
    for (int ni = 0; ni < 2; ++ni) bv[ni] = bias[n0 + wc * 64 + ni * 32 + ln31];
#pragma unroll
    for (int mi = 0; mi < 4; ++mi)
#pragma unroll
      for (int ni = 0; ni < 2; ++ni) {
        const int colg = n0 + wc * 64 + ni * 32 + ln31;
#pragma unroll
        for (int r = 0; r < 16; ++r) {
          const int rowg = m0 + wr * 128 + mi * 32 + (r & 3) + 8 * (r >> 2) + 4 * hi;
          C[(size_t)rowg * N + colg] = acc[mi][ni][r] + bv[ni];
        }
      }
  }
}

// ---------------- launch ----------------

extern "C" void kernel_launch(void* const* d_in, const int* in_sizes, int n_in,
                              void* d_out, int out_size, void* d_ws, size_t ws_size,
                              hipStream_t stream) {
  const float* x = (const float*)d_in[0];        // [B,S,D] = [4,2048,4096] f32
  const int* indices = (const int*)d_in[1];      // [O,D] = [4096,4096] i32
  const float* codebook = (const float*)d_in[2]; // [16] f32
  const float* rot = (const float*)d_in[3];      // [K,D] = [4096,4096] f32
  const float* bias = (const float*)d_in[4];     // [O] f32
  float* out = (float*)d_out;                    // [B*S, O] f32

  const int D = 4096, O = 4096;
  const int M = in_sizes[0] / D;  // 8192

  char* ws = (char*)d_ws;
  __hip_bfloat16* Xb = (__hip_bfloat16*)ws;                          // 64MB: [M,D] bf16
  __hip_bfloat16* Rb = (__hip_bfloat16*)(ws + ((size_t)64 << 20));   // 32MB: [K,D] bf16
  __hip_bfloat16* Wr = (__hip_bfloat16*)(ws + ((size_t)96 << 20));   // 32MB: [O,D] bf16
  __hip_bfloat16* Wb = (__hip_bfloat16*)(ws + ((size_t)128 << 20));  // 32MB: [O,K] bf16

  cvt_f32_bf16<<<(M * D / 4 + 255) / 256, 256, 0, stream>>>(x, Xb, M * D / 4);
  cvt_f32_bf16<<<(4096 * 4096 / 4 + 255) / 256, 256, 0, stream>>>(rot, Rb, 4096 * 4096 / 4);
  dequant_bf16<<<(4096 * 4096 / 4 + 255) / 256, 256, 0, stream>>>(indices, codebook, Wr,
                                                                  4096 * 4096 / 4);

  // GEMM1: Wb[o,k] = sum_d Wr[o,d] * Rb[k,d]   (4096^3, bf16 out)
  gemm256<true><<<dim3((O / 256) * (4096 / 256)), 512, 0, stream>>>(Wr, Rb, Wb, nullptr, O, 4096,
                                                                    D);
  // GEMM2: out[m,o] = sum_k Xb[m,k] * Wb[o,k] + bias[o]   (8192x4096x4096, f32 out)
  gemm256<false><<<dim3((M / 256) * (O / 256)), 512, 0, stream>>>(Xb, Wb, out, bias, M, O, 4096);
}

// Round 8
// 437.235 us; speedup vs baseline: 1.5513x; 1.5513x over previous
//
#include <hip/hip_runtime.h>
#include <hip/hip_bf16.h>

// out[b,s,o] = sum_k x[b,s,k] * W[o,k] + bias[o],  W[o,k] = sum_d codebook[idx[o,d]] * rot[k,d]
// bf16 path: dequant+convert, GEMM1 (W = Wr @ R^T, bf16 out), GEMM2 (out = X @ W^T + bias, f32).
// R8: R5 geometry (256x256, BK=64, 8 waves 2Mx4N, 16x16x32 MFMA, reads 8/8/4/4, stage 1
// half-tile/phase, counted vmcnt) but SINGLE barrier per phase: closing barriers removed so
// phase-p+1 ds_reads issue right after each wave's own phase-p MFMA and drain under other
// waves' MFMA tail + barrier skew (LDS port || MFMA overlap that the 2-barrier phase forbade).
// Hazards: (1) stage-vs-read: stages issue POST-barrier; all waves' last reads of the target
// region drained at their pre-barrier lgkm(0) of the last-reader phase, sequenced by that
// barrier. A(T+1)->idle buf (last read T-1.ph3, certified by BAR(T.ph0)); B(T+2)->current buf
// B-region (last read T.ph1, certified by BAR(T.ph2)). (2) fresh-data reads: per-wave
// vmcnt(4|0) pre-BAR(ph0) certifies tile T fully (leaves B(T+1)'s 4 loads in flight); ph0's
// reads therefore issue POST-barrier (only phase paying serial read drain).

typedef __attribute__((ext_vector_type(8))) __bf16 bf16x8;
typedef __attribute__((ext_vector_type(4))) float f32x4;

#define GLOAD_LDS16(g, l)                                                        \
  __builtin_amdgcn_global_load_lds((__attribute__((address_space(1))) void*)(g), \
                                   (__attribute__((address_space(3))) void*)(l), \
                                   16, 0, 0)

// ---------------- conversion kernels ----------------

__global__ __launch_bounds__(256) void cvt_f32_bf16(const float* __restrict__ in,
                                                    __hip_bfloat16* __restrict__ out, int n4) {
  int i = blockIdx.x * 256 + threadIdx.x;
  if (i >= n4) return;
  float4 v = *(const float4*)(in + (size_t)i * 4);
  union { __hip_bfloat16 h[4]; ushort4 u; } o;
  o.h[0] = __float2bfloat16(v.x);
  o.h[1] = __float2bfloat16(v.y);
  o.h[2] = __float2bfloat16(v.z);
  o.h[3] = __float2bfloat16(v.w);
  *(ushort4*)((unsigned short*)out + (size_t)i * 4) = o.u;
}

__global__ __launch_bounds__(256) void dequant_bf16(const int* __restrict__ idx,
                                                    const float* __restrict__ cb,
                                                    __hip_bfloat16* __restrict__ out, int n4) {
  __shared__ __hip_bfloat16 scb[16];
  if (threadIdx.x < 16) scb[threadIdx.x] = __float2bfloat16(cb[threadIdx.x]);
  __syncthreads();
  int i = blockIdx.x * 256 + threadIdx.x;
  if (i >= n4) return;
  int4 v = *(const int4*)(idx + (size_t)i * 4);
  union { __hip_bfloat16 h[4]; ushort4 u; } o;
  o.h[0] = scb[v.x & 15];
  o.h[1] = scb[v.y & 15];
  o.h[2] = scb[v.z & 15];
  o.h[3] = scb[v.w & 15];
  *(ushort4*)((unsigned short*)out + (size_t)i * 4) = o.u;
}

// ---------------- 256^2 4-phase (1-barrier) NT bf16 GEMM: C = A[M,K] @ B[N,K]^T -------------

template <bool OUT_BF16>
__global__ __launch_bounds__(512, 2) void gemm256(const __hip_bfloat16* __restrict__ A,
                                                  const __hip_bfloat16* __restrict__ B,
                                                  void* __restrict__ Cv,
                                                  const float* __restrict__ bias,
                                                  int M, int N, int K) {
  __shared__ __align__(16) char smem[131072];

  const int nbn = N >> 8;
  const int nwg = (M >> 8) * nbn;
  const int bid0 = blockIdx.x;
  const int cpx = nwg >> 3;  // nwg % 8 == 0 for our shapes -> bijective XCD swizzle
  const int bid = (bid0 & 7) * cpx + (bid0 >> 3);
  const int m0 = (bid / nbn) << 8;
  const int n0 = (bid % nbn) << 8;

  const int tid = (int)threadIdx.x;
  const int lane = tid & 63;
  const int w = tid >> 6;   // wave 0..7
  const int wr = w >> 2;    // 0..1 -> 128 rows
  const int wc = w & 3;     // 0..3 -> 64 cols
  const int fr = lane & 15;
  const int fq = lane >> 4;

  // staging lane pattern: srow = row within 8-row stripe, scol = inverse-swizzled col
  const int srow = lane >> 3;                 // 0..7
  const int scol = ((lane & 7) ^ srow) << 3;  // element offset within 64-col row

  const __hip_bfloat16* Ab = A + (size_t)m0 * K;
  const __hip_bfloat16* Bb = B + (size_t)n0 * K;

  const int NT = K >> 6;

  f32x4 acc[8][4];
#pragma unroll
  for (int i = 0; i < 8; ++i)
#pragma unroll
    for (int j = 0; j < 4; ++j) acc[i][j] = (f32x4){0.f, 0.f, 0.f, 0.f};

  // stage half-tile s = 4*t + kind (kind: 0=A-half0, 1=A-half1, 2=B-half0, 3=B-half1)
  auto stage = [&](int s) {
    const int t = s >> 2, kind = s & 3;
    const __hip_bfloat16* g = (kind < 2) ? Ab : Bb;
    char* region = smem + ((kind < 2) ? 0 : 65536) + (t & 1) * 32768 + (kind & 1) * 16384;
    const int grow = (kind & 1) * 128 + w * 16 + srow;
    const int k0 = t << 6;
#pragma unroll
    for (int j = 0; j < 2; ++j)
      GLOAD_LDS16(g + (size_t)(grow + j * 8) * K + (k0 + scol), region + w * 2048 + j * 1024);
  };

  const int sw = (fr & 7) << 4;  // read-side swizzle XOR (row&7 == fr&7 for all frag rows)

  auto ldA = [&](int b, int mh, int mf, int kk) -> bf16x8 {
    const int row = wr * 128 + mh * 64 + mf * 16 + fr;
    const int byte = b * 32768 + row * 128 + ((kk * 64 + fq * 16) ^ sw);
    return *(const bf16x8*)(smem + byte);
  };
  auto ldB = [&](int b, int nf, int kk) -> bf16x8 {
    const int row = wc * 64 + nf * 16 + fr;
    const int byte = 65536 + b * 32768 + row * 128 + ((kk * 64 + fq * 16) ^ sw);
    return *(const bf16x8*)(smem + byte);
  };

  // prologue: tile0 fully + B(1) (12 gloads/wave); loop ph0's vmcnt(4)+BAR certifies tile0
  stage(0); stage(1); stage(2); stage(3);
  stage(6); stage(7);

  bf16x8 afA[4], afB[4], bk0[4], bk1[4];

  for (int T = 0; T < NT; ++T) {
    const int b = T & 1;
    const bool pf1 = (T + 1 < NT);
    const bool pf2 = (T + 2 < NT);

    // ---- ph0 (single barrier; reads POST-bar: freshly certified data)
    if (T + 1 == NT) {
      asm volatile("s_waitcnt vmcnt(0)" ::: "memory");
    } else {
      asm volatile("s_waitcnt vmcnt(4)" ::: "memory");
    }
    __builtin_amdgcn_s_barrier();
#pragma unroll
    for (int mf = 0; mf < 4; ++mf) afA[mf] = ldA(b, 0, mf, 0);
#pragma unroll
    for (int nf = 0; nf < 4; ++nf) bk0[nf] = ldB(b, nf, 0);
    if (pf1) stage(4 * (T + 1) + 0);  // A0(T+1) -> idle buf (last read T-1.ph3, certified)
    asm volatile("s_waitcnt lgkmcnt(0)");
    __builtin_amdgcn_sched_barrier(0);
    __builtin_amdgcn_s_setprio(1);
#pragma unroll
    for (int nf = 0; nf < 4; ++nf)
#pragma unroll
      for (int mf = 0; mf < 4; ++mf)
        acc[mf][nf] = __builtin_amdgcn_mfma_f32_16x16x32_bf16(afA[mf], bk0[nf], acc[mf][nf], 0, 0, 0);
    __builtin_amdgcn_s_setprio(0);

    // ---- ph1: reads pre-bar (overlap other waves' ph0 MFMA); stage A1(T+1) post-bar
#pragma unroll
    for (int mf = 0; mf < 4; ++mf) afB[mf] = ldA(b, 0, mf, 1);
#pragma unroll
    for (int nf = 0; nf < 4; ++nf) bk1[nf] = ldB(b, nf, 1);
    __builtin_amdgcn_s_barrier();
    if (pf1) stage(4 * (T + 1) + 1);
    asm volatile("s_waitcnt lgkmcnt(0)");
    __builtin_amdgcn_sched_barrier(0);
    __builtin_amdgcn_s_setprio(1);
#pragma unroll
    for (int nf = 0; nf < 4; ++nf)
#pragma unroll
      for (int mf = 0; mf < 4; ++mf)
        acc[mf][nf] = __builtin_amdgcn_mfma_f32_16x16x32_bf16(afB[mf], bk1[nf], acc[mf][nf], 0, 0, 0);
    __builtin_amdgcn_s_setprio(0);

    // ---- ph2: reads pre-bar; stage B0(T+2) -> current-buf B-region (last read ph1,
    //          certified by this barrier) post-bar
#pragma unroll
    for (int mf = 0; mf < 4; ++mf) afA[mf] = ldA(b, 1, mf, 0);
    __builtin_amdgcn_s_barrier();
    if (pf2) stage(4 * (T + 2) + 2);
    asm volatile("s_waitcnt lgkmcnt(0)");
    __builtin_amdgcn_sched_barrier(0);
    __builtin_amdgcn_s_setprio(1);
#pragma unroll
    for (int nf = 0; nf < 4; ++nf)
#pragma unroll
      for (int mf = 0; mf < 4; ++mf)
        acc[4 + mf][nf] = __builtin_amdgcn_mfma_f32_16x16x32_bf16(afA[mf], bk0[nf], acc[4 + mf][nf], 0, 0, 0);
    __builtin_amdgcn_s_setprio(0);

    // ---- ph3: reads pre-bar; stage B1(T+2) post-bar
#pragma unroll
    for (int mf = 0; mf < 4; ++mf) afB[mf] = ldA(b, 1, mf, 1);
    __builtin_amdgcn_s_barrier();
    if (pf2) stage(4 * (T + 2) + 3);
    asm volatile("s_waitcnt lgkmcnt(0)");
    __builtin_amdgcn_sched_barrier(0);
    __builtin_amdgcn_s_setprio(1);
#pragma unroll
    for (int nf = 0; nf < 4; ++nf)
#pragma unroll
      for (int mf = 0; mf < 4; ++mf)
        acc[4 + mf][nf] = __builtin_amdgcn_mfma_f32_16x16x32_bf16(afB[mf], bk1[nf], acc[4 + mf][nf], 0, 0, 0);
    __builtin_amdgcn_s_setprio(0);
    // next iteration's ph0 vmcnt+barrier closes the tile
  }

  // ---- epilogue: C/D layout col = lane&15 (n-side), row = fq*4 + v (m-side)
  if constexpr (OUT_BF16) {
    __hip_bfloat16* C = (__hip_bfloat16*)Cv;
#pragma unroll
    for (int mi = 0; mi < 8; ++mi)
#pragma unroll
      for (int ni = 0; ni < 4; ++ni) {
        const size_t row = (size_t)(m0 + wr * 128 + (mi >> 2) * 64 + (mi & 3) * 16 + fq * 4);
        const int col = n0 + wc * 64 + ni * 16 + fr;
#pragma unroll
        for (int v = 0; v < 4; ++v) C[(row + v) * N + col] = __float2bfloat16(acc[mi][ni][v]);
      }
  } else {
    float* C = (float*)Cv;
    float bv[4];
#pragma unroll
    for (int ni = 0; ni < 4; ++ni) bv[ni] = bias[n0 + wc * 64 + ni * 16 + fr];
#pragma unroll
    for (int mi = 0; mi < 8; ++mi)
#pragma unroll
      for (int ni = 0; ni < 4; ++ni) {
        const size_t row = (size_t)(m0 + wr * 128 + (mi >> 2) * 64 + (mi & 3) * 16 + fq * 4);
        const int col = n0 + wc * 64 + ni * 16 + fr;
#pragma unroll
        for (int v = 0; v < 4; ++v) C[(row + v) * N + col] = acc[mi][ni][v] + bv[ni];
      }
  }
}

// ---------------- launch ----------------

extern "C" void kernel_launch(void* const* d_in, const int* in_sizes, int n_in,
                              void* d_out, int out_size, void* d_ws, size_t ws_size,
                              hipStream_t stream) {
  const float* x = (const float*)d_in[0];        // [B,S,D] = [4,2048,4096] f32
  const int* indices = (const int*)d_in[1];      // [O,D] = [4096,4096] i32
  const float* codebook = (const float*)d_in[2]; // [16] f32
  const float* rot = (const float*)d_in[3];      // [K,D] = [4096,4096] f32
  const float* bias = (const float*)d_in[4];     // [O] f32
  float* out = (float*)d_out;                    // [B*S, O] f32

  const int D = 4096, O = 4096;
  const int M = in_sizes[0] / D;  // 8192

  char* ws = (char*)d_ws;
  __hip_bfloat16* Xb = (__hip_bfloat16*)ws;                          // 64MB: [M,D] bf16
  __hip_bfloat16* Rb = (__hip_bfloat16*)(ws + ((size_t)64 << 20));   // 32MB: [K,D] bf16
  __hip_bfloat16* Wr = (__hip_bfloat16*)(ws + ((size_t)96 << 20));   // 32MB: [O,D] bf16
  __hip_bfloat16* Wb = (__hip_bfloat16*)(ws + ((size_t)128 << 20));  // 32MB: [O,K] bf16

  cvt_f32_bf16<<<(M * D / 4 + 255) / 256, 256, 0, stream>>>(x, Xb, M * D / 4);
  cvt_f32_bf16<<<(4096 * 4096 / 4 + 255) / 256, 256, 0, stream>>>(rot, Rb, 4096 * 4096 / 4);
  dequant_bf16<<<(4096 * 4096 / 4 + 255) / 256, 256, 0, stream>>>(indices, codebook, Wr,
                                                                  4096 * 4096 / 4);

  // GEMM1: Wb[o,k] = sum_d Wr[o,d] * Rb[k,d]   (4096^3, bf16 out)
  gemm256<true><<<dim3((O / 256) * (4096 / 256)), 512, 0, stream>>>(Wr, Rb, Wb, nullptr, O, 4096,
                                                                    D);
  // GEMM2: out[m,o] = sum_k Xb[m,k] * Wb[o,k] + bias[o]   (8192x4096x4096, f32 out)
  gemm256<false><<<dim3((M / 256) * (O / 256)), 512, 0, stream>>>(Xb, Wb, out, bias, M, O, 4096);
}